// Round 1
// baseline (387.468 us; speedup 1.0000x reference)
//
#include <hip/hip_runtime.h>
#include <math.h>

#define LOG2E 1.4426950408889634f

typedef __attribute__((ext_vector_type(8))) short short8;
typedef __attribute__((ext_vector_type(4))) float floatx4;

__device__ __forceinline__ unsigned short f2bf(float f) {
  union { float f; unsigned int u; } v; v.f = f;
  unsigned int r = v.u + 0x7fffu + ((v.u >> 16) & 1u);
  return (unsigned short)(r >> 16);
}

__device__ __forceinline__ unsigned int pack2(unsigned short a, unsigned short b) {
  return (unsigned int)a | ((unsigned int)b << 16);
}

// async global->LDS, 16B per lane. LDS dest is wave-uniform base + lane*16.
__device__ __forceinline__ void async16(const unsigned short* gp, unsigned short* lp) {
  __builtin_amdgcn_global_load_lds(
      (__attribute__((address_space(1))) void*)(gp),
      (__attribute__((address_space(3))) void*)(lp), 16, 0, 0);
}

// ---------------------------------------------------------------- GroupNorm
// one block per (b,g): 2*32 = 64 blocks; group = 16 ch * 4096 = 65536 contiguous floats
__global__ void gn_stats(const float* __restrict__ x, float* __restrict__ stats) {
  int bg = blockIdx.x;
  const float4* p = (const float4*)(x + (size_t)bg * 65536);
  float s = 0.f, ss = 0.f;
  for (int i = threadIdx.x; i < 16384; i += 256) {
    float4 v = p[i];
    s  += v.x + v.y + v.z + v.w;
    ss += v.x*v.x + v.y*v.y + v.z*v.z + v.w*v.w;
  }
  #pragma unroll
  for (int off = 32; off >= 1; off >>= 1) {
    s  += __shfl_xor(s,  off, 64);
    ss += __shfl_xor(ss, off, 64);
  }
  __shared__ float red[2][4];
  int wv = threadIdx.x >> 6;
  if ((threadIdx.x & 63) == 0) { red[0][wv] = s; red[1][wv] = ss; }
  __syncthreads();
  if (threadIdx.x == 0) {
    s  = red[0][0] + red[0][1] + red[0][2] + red[0][3];
    ss = red[1][0] + red[1][1] + red[1][2] + red[1][3];
    float mean = s * (1.f/65536.f);
    float var  = ss * (1.f/65536.f) - mean*mean;
    stats[2*bg]   = mean;
    stats[2*bg+1] = rsqrtf(var + 1e-5f);
  }
}

// normalize + cast bf16 + transpose to token-major h_t[B][HW][C]
__global__ void gn_apply_t(const float* __restrict__ x, const float* __restrict__ stats,
                           const float* __restrict__ gw, const float* __restrict__ gb,
                           unsigned short* __restrict__ h_t) {
  __shared__ __align__(16) unsigned short tile[64][72];
  const int b = blockIdx.z, c0 = blockIdx.y * 64, hw0 = blockIdx.x * 64;
  const int t = threadIdx.x;
  {
    const int cl = t >> 2;
    const int hs = (t & 3) * 16;
    const int c  = c0 + cl;
    const int g  = c >> 4;
    const float mean = stats[2*(b*32 + g)];
    const float rstd = stats[2*(b*32 + g) + 1];
    const float w  = gw[c] * rstd;
    const float bb = gb[c] - mean * w;
    const float4* src = (const float4*)(x + ((size_t)(b*512 + c))*4096 + hw0 + hs);
    #pragma unroll
    for (int i = 0; i < 4; i++) {
      float4 vv = src[i];
      unsigned short* d = &tile[cl][hs + i*4];
      d[0] = f2bf(vv.x*w + bb); d[1] = f2bf(vv.y*w + bb);
      d[2] = f2bf(vv.z*w + bb); d[3] = f2bf(vv.w*w + bb);
    }
  }
  __syncthreads();
  {
    const int hwl = t >> 2;
    const int cs  = (t & 3) * 16;
    uint4 w0, w1;
    w0.x = pack2(tile[cs+ 0][hwl], tile[cs+ 1][hwl]);
    w0.y = pack2(tile[cs+ 2][hwl], tile[cs+ 3][hwl]);
    w0.z = pack2(tile[cs+ 4][hwl], tile[cs+ 5][hwl]);
    w0.w = pack2(tile[cs+ 6][hwl], tile[cs+ 7][hwl]);
    w1.x = pack2(tile[cs+ 8][hwl], tile[cs+ 9][hwl]);
    w1.y = pack2(tile[cs+10][hwl], tile[cs+11][hwl]);
    w1.z = pack2(tile[cs+12][hwl], tile[cs+13][hwl]);
    w1.w = pack2(tile[cs+14][hwl], tile[cs+15][hwl]);
    unsigned short* dst = h_t + ((size_t)(b*4096 + hw0 + hwl))*512 + c0 + cs;
    *(uint4*)dst       = w0;
    *(uint4*)(dst + 8) = w1;
  }
}

// fp32 -> bf16 weight cast, n4 float4s
__global__ void castw(const float* __restrict__ src, unsigned short* __restrict__ dst, int n4) {
  int i = blockIdx.x * 256 + threadIdx.x;
  if (i < n4) {
    float4 vv = ((const float4*)src)[i];
    uint2 o;
    o.x = pack2(f2bf(vv.x), f2bf(vv.y));
    o.y = pack2(f2bf(vv.z), f2bf(vv.w));
    ((uint2*)dst)[i] = o;
  }
}

// ---------------------------------------------------------------- GEMM (bt)
// OUT[o][n] = sum_k A[o][k] * Bt[n][k];  A row-major [O][512], Bt token-major [4096][512] per batch
// MODE 0: qkv epilogue -> q_t/k_t/v scatter (legacy per-head [q,k,v] blocks of 64)
// MODE 1: proj epilogue -> out = x + bias + acc  (fp32)
template <int MODE>
__global__ __launch_bounds__(256, 2)
void gemm_bt(const unsigned short* __restrict__ A,
             const unsigned short* __restrict__ Bt,
             unsigned short* __restrict__ q_t,
             unsigned short* __restrict__ k_t,
             unsigned short* __restrict__ v_,
             float* __restrict__ outp,
             const float* __restrict__ xres,
             const float* __restrict__ pbias) {
  __shared__ __align__(16) unsigned short As[128*32];
  __shared__ __align__(16) unsigned short Bs[128*32];
  const int b   = blockIdx.z;
  const int n0  = blockIdx.x * 128;
  const int o0  = blockIdx.y * 128;
  const int tid = threadIdx.x;
  const int wave = tid >> 6, lane = tid & 63;
  const int wr = wave >> 1, wc = wave & 1;
  const int fm = lane & 15, fq = lane >> 4;
  const int srow = lane >> 2, scol = (lane & 3) * 8;

  const unsigned short* Ab = A + (size_t)o0 * 512;
  const unsigned short* Bb = Bt + ((size_t)b*4096 + n0) * 512;

  floatx4 acc[4][4];
  #pragma unroll
  for (int i = 0; i < 4; i++)
    #pragma unroll
    for (int j = 0; j < 4; j++) acc[i][j] = (floatx4){0.f,0.f,0.f,0.f};

  for (int k0 = 0; k0 < 512; k0 += 32) {
    __syncthreads();
    #pragma unroll
    for (int cc = 0; cc < 2; cc++) {
      int ch = wave*2 + cc;
      async16(Ab + (size_t)(ch*16 + srow)*512 + k0 + scol, &As[ch*512]);
      async16(Bb + (size_t)(ch*16 + srow)*512 + k0 + scol, &Bs[ch*512]);
    }
    __syncthreads();
    short8 af[4], bf[4];
    #pragma unroll
    for (int f = 0; f < 4; f++) {
      af[f] = *(const short8*)&As[(wr*64 + f*16 + fm)*32 + fq*8];
      bf[f] = *(const short8*)&Bs[(wc*64 + f*16 + fm)*32 + fq*8];
    }
    #pragma unroll
    for (int fr = 0; fr < 4; fr++)
      #pragma unroll
      for (int fc = 0; fc < 4; fc++)
        acc[fr][fc] = __builtin_amdgcn_mfma_f32_16x16x32_bf16(af[fr], bf[fc], acc[fr][fc], 0, 0, 0);
  }

  if (MODE == 0) {
    #pragma unroll
    for (int fr = 0; fr < 4; fr++) {
      const int ob     = o0 + wr*64 + fr*16;   // frag fits in one head+region
      const int head   = ob / 192;
      const int rem    = ob % 192;
      const int region = rem >> 6;             // 0=q 1=k 2=v
      const int dsub   = (rem & 63) + fq*4;
      const int bhh    = b*8 + head;
      #pragma unroll
      for (int fc = 0; fc < 4; fc++) {
        const int i = n0 + wc*64 + fc*16 + fm;
        if (region == 0) {
          unsigned short t4[4];
          #pragma unroll
          for (int r = 0; r < 4; r++) t4[r] = f2bf(acc[fr][fc][r] * 0.125f); // both scales folded
          uint2 o; o.x = pack2(t4[0], t4[1]); o.y = pack2(t4[2], t4[3]);
          *(uint2*)&q_t[((size_t)bhh*4096 + i)*64 + dsub] = o;
        } else if (region == 1) {
          unsigned short t4[4];
          #pragma unroll
          for (int r = 0; r < 4; r++) t4[r] = f2bf(acc[fr][fc][r]);
          uint2 o; o.x = pack2(t4[0], t4[1]); o.y = pack2(t4[2], t4[3]);
          *(uint2*)&k_t[((size_t)bhh*4096 + i)*64 + dsub] = o;
        } else {
          #pragma unroll
          for (int r = 0; r < 4; r++)
            v_[((size_t)bhh*64 + dsub + r)*4096 + i] = f2bf(acc[fr][fc][r]);
        }
      }
    }
  } else {
    #pragma unroll
    for (int fr = 0; fr < 4; fr++)
      #pragma unroll
      for (int fc = 0; fc < 4; fc++) {
        const int i = n0 + wc*64 + fc*16 + fm;
        #pragma unroll
        for (int r = 0; r < 4; r++) {
          const int o = o0 + wr*64 + fr*16 + fq*4 + r;
          const size_t idx = ((size_t)b*512 + o)*4096 + i;
          outp[idx] = xres[idx] + pbias[o] + acc[fr][fc][r];
        }
      }
  }
}

// ---------------------------------------------------------------- attention
// q_t,k_t: [16][4096][64] bf16 (q pre-scaled by 1/8); v: [16][64][4096] bf16
// out hout_t: [2][4096][512] bf16 token-major
__global__ __launch_bounds__(256, 2)
void attn_kernel(const unsigned short* __restrict__ q_t,
                 const unsigned short* __restrict__ k_t,
                 const unsigned short* __restrict__ v_,
                 unsigned short* __restrict__ hout_t) {
  __shared__ __align__(16) unsigned short Ks[64*72];   // [j][d], +16B row pad
  __shared__ __align__(16) unsigned short Vs[64*72];   // [d][j], +16B row pad
  __shared__ __align__(16) unsigned short Ps[4][16*72];// per-wave P [row][j]

  const int bh  = blockIdx.x;       // x = bh so XCD L2 holds ~2 heads' K/V
  const int q0  = blockIdx.y * 64;
  const int tid = threadIdx.x;
  const int wave = tid >> 6, lane = tid & 63;
  const int fm = lane & 15, fq = lane >> 4;

  // Q fragments live in registers for the whole K-loop
  const unsigned short* qrow = q_t + ((size_t)bh*4096 + q0 + wave*16 + fm)*64;
  const short8 qf0 = *(const short8*)(qrow + fq*8);
  const short8 qf1 = *(const short8*)(qrow + 32 + fq*8);

  floatx4 o_acc[4];
  #pragma unroll
  for (int i = 0; i < 4; i++) o_acc[i] = (floatx4){0.f,0.f,0.f,0.f};
  float m_i[4], l_i[4];
  #pragma unroll
  for (int r = 0; r < 4; r++) { m_i[r] = -1e30f; l_i[r] = 0.f; }

  const int sr = tid >> 3;
  const int sc = (tid & 7) * 8;
  const unsigned short* kbase = k_t + (size_t)bh*4096*64;
  const unsigned short* vbase = v_  + (size_t)bh*64*4096;

  for (int j0 = 0; j0 < 4096; j0 += 64) {
    __syncthreads();
    {
      const unsigned short* ksrc = kbase + (size_t)j0*64;
      *(uint4*)&Ks[sr*72 + sc]      = *(const uint4*)&ksrc[(size_t)sr*64 + sc];
      *(uint4*)&Ks[(sr+32)*72 + sc] = *(const uint4*)&ksrc[(size_t)(sr+32)*64 + sc];
      const unsigned short* vsrc = vbase + j0;
      *(uint4*)&Vs[sr*72 + sc]      = *(const uint4*)&vsrc[(size_t)sr*4096 + sc];
      *(uint4*)&Vs[(sr+32)*72 + sc] = *(const uint4*)&vsrc[(size_t)(sr+32)*4096 + sc];
    }
    __syncthreads();

    floatx4 s_acc[4];
    #pragma unroll
    for (int fc = 0; fc < 4; fc++) {
      s_acc[fc] = (floatx4){0.f,0.f,0.f,0.f};
      short8 kf0 = *(const short8*)&Ks[(fc*16 + fm)*72 + fq*8];
      short8 kf1 = *(const short8*)&Ks[(fc*16 + fm)*72 + 32 + fq*8];
      s_acc[fc] = __builtin_amdgcn_mfma_f32_16x16x32_bf16(qf0, kf0, s_acc[fc], 0, 0, 0);
      s_acc[fc] = __builtin_amdgcn_mfma_f32_16x16x32_bf16(qf1, kf1, s_acc[fc], 0, 0, 0);
    }

    // online softmax in exp2 domain; rows fq*4+r, 64 cols spread over 16 lanes x 4 fc
    #pragma unroll
    for (int r = 0; r < 4; r++) {
      float s0 = s_acc[0][r]*LOG2E, s1 = s_acc[1][r]*LOG2E;
      float s2 = s_acc[2][r]*LOG2E, s3 = s_acc[3][r]*LOG2E;
      float mx = fmaxf(fmaxf(s0, s1), fmaxf(s2, s3));
      #pragma unroll
      for (int off = 1; off <= 8; off <<= 1) mx = fmaxf(mx, __shfl_xor(mx, off, 64));
      float mnew  = fmaxf(m_i[r], mx);
      float alpha = exp2f(m_i[r] - mnew);
      m_i[r] = mnew;
      float p0 = exp2f(s0 - mnew), p1 = exp2f(s1 - mnew);
      float p2 = exp2f(s2 - mnew), p3 = exp2f(s3 - mnew);
      float sum = p0 + p1 + p2 + p3;
      #pragma unroll
      for (int off = 1; off <= 8; off <<= 1) sum += __shfl_xor(sum, off, 64);
      l_i[r] = l_i[r]*alpha + sum;
      #pragma unroll
      for (int fd = 0; fd < 4; fd++) o_acc[fd][r] *= alpha;
      const int prow = (fq*4 + r)*72;
      Ps[wave][prow + 0*16 + fm] = f2bf(p0);
      Ps[wave][prow + 1*16 + fm] = f2bf(p1);
      Ps[wave][prow + 2*16 + fm] = f2bf(p2);
      Ps[wave][prow + 3*16 + fm] = f2bf(p3);
    }
    __syncthreads();

    short8 pf0 = *(const short8*)&Ps[wave][fm*72 + fq*8];
    short8 pf1 = *(const short8*)&Ps[wave][fm*72 + 32 + fq*8];
    #pragma unroll
    for (int fd = 0; fd < 4; fd++) {
      short8 vf0 = *(const short8*)&Vs[(fd*16 + fm)*72 + fq*8];
      short8 vf1 = *(const short8*)&Vs[(fd*16 + fm)*72 + 32 + fq*8];
      o_acc[fd] = __builtin_amdgcn_mfma_f32_16x16x32_bf16(pf0, vf0, o_acc[fd], 0, 0, 0);
      o_acc[fd] = __builtin_amdgcn_mfma_f32_16x16x32_bf16(pf1, vf1, o_acc[fd], 0, 0, 0);
    }
  }

  const int bb = bh >> 3;
  const int cb = (bh & 7) * 64;
  #pragma unroll
  for (int fd = 0; fd < 4; fd++) {
    #pragma unroll
    for (int r = 0; r < 4; r++) {
      const int i = q0 + wave*16 + fq*4 + r;
      const int c = cb + fd*16 + fm;
      hout_t[((size_t)bb*4096 + i)*512 + c] = f2bf(o_acc[fd][r] / l_i[r]);
    }
  }
}

// ---------------------------------------------------------------- launcher
extern "C" void kernel_launch(void* const* d_in, const int* in_sizes, int n_in,
                              void* d_out, int out_size, void* d_ws, size_t ws_size,
                              hipStream_t stream) {
  (void)in_sizes; (void)n_in; (void)out_size; (void)ws_size;
  const float* x      = (const float*)d_in[0];
  const float* qkv_w  = (const float*)d_in[1];
  const float* proj_w = (const float*)d_in[2];
  const float* proj_b = (const float*)d_in[3];
  const float* gn_w   = (const float*)d_in[4];
  const float* gn_b   = (const float*)d_in[5];
  float* out = (float*)d_out;

  char* ws = (char*)d_ws;
  unsigned short* h_t   = (unsigned short*)(ws);                     // 8 MB, reused as hout_t
  unsigned short* q_t   = (unsigned short*)(ws + ((size_t)8  << 20));
  unsigned short* k_t   = (unsigned short*)(ws + ((size_t)16 << 20));
  unsigned short* v_    = (unsigned short*)(ws + ((size_t)24 << 20));
  unsigned short* wqkv  = (unsigned short*)(ws + ((size_t)32 << 20)); // 1.5 MB
  unsigned short* wproj = (unsigned short*)(ws + ((size_t)34 << 20)); // 0.5 MB
  float* stats          = (float*)(ws + ((size_t)35 << 20));          // 512 B
  unsigned short* hout_t = h_t;

  gn_stats<<<dim3(64), dim3(256), 0, stream>>>(x, stats);
  gn_apply_t<<<dim3(64, 8, 2), dim3(256), 0, stream>>>(x, stats, gn_w, gn_b, h_t);
  castw<<<dim3(768), dim3(256), 0, stream>>>(qkv_w, wqkv, 196608);
  castw<<<dim3(256), dim3(256), 0, stream>>>(proj_w, wproj, 65536);
  gemm_bt<0><<<dim3(32, 12, 2), dim3(256), 0, stream>>>(wqkv, h_t, q_t, k_t, v_,
                                                        nullptr, nullptr, nullptr);
  attn_kernel<<<dim3(16, 64), dim3(256), 0, stream>>>(q_t, k_t, v_, hout_t);
  gemm_bt<1><<<dim3(32, 4, 2), dim3(256), 0, stream>>>(wproj, hout_t,
                                                       nullptr, nullptr, nullptr,
                                                       out, x, proj_b);
}

// Round 2
// 279.754 us; speedup vs baseline: 1.3850x; 1.3850x over previous
//
#include <hip/hip_runtime.h>
#include <math.h>

typedef __attribute__((ext_vector_type(8))) short short8;
typedef __attribute__((ext_vector_type(4))) float floatx4;

__device__ __forceinline__ unsigned short f2bf(float f) {
  union { float f; unsigned int u; } v; v.f = f;
  unsigned int r = v.u + 0x7fffu + ((v.u >> 16) & 1u);
  return (unsigned short)(r >> 16);
}

__device__ __forceinline__ unsigned int pack2(unsigned short a, unsigned short b) {
  return (unsigned int)a | ((unsigned int)b << 16);
}

__device__ __forceinline__ unsigned int rbits(float f) {
  union { float f; unsigned int u; } v; v.f = f;
  return v.u + 0x8000u;  // round-half-up to bf16 when >>16
}

__device__ __forceinline__ float fast_exp2(float x) {
#if __has_builtin(__builtin_amdgcn_exp2f)
  return __builtin_amdgcn_exp2f(x);
#else
  return exp2f(x);
#endif
}

// async global->LDS, 16B per lane. LDS dest is wave-uniform base + lane*16.
__device__ __forceinline__ void async16(const unsigned short* gp, unsigned short* lp) {
  __builtin_amdgcn_global_load_lds(
      (__attribute__((address_space(1))) void*)(gp),
      (__attribute__((address_space(3))) void*)(lp), 16, 0, 0);
}

// ---------------------------------------------------------------- GroupNorm
__global__ void gn_stats(const float* __restrict__ x, float* __restrict__ stats) {
  int bg = blockIdx.x;
  const float4* p = (const float4*)(x + (size_t)bg * 65536);
  float s = 0.f, ss = 0.f;
  for (int i = threadIdx.x; i < 16384; i += 256) {
    float4 v = p[i];
    s  += v.x + v.y + v.z + v.w;
    ss += v.x*v.x + v.y*v.y + v.z*v.z + v.w*v.w;
  }
  #pragma unroll
  for (int off = 32; off >= 1; off >>= 1) {
    s  += __shfl_xor(s,  off, 64);
    ss += __shfl_xor(ss, off, 64);
  }
  __shared__ float red[2][4];
  int wv = threadIdx.x >> 6;
  if ((threadIdx.x & 63) == 0) { red[0][wv] = s; red[1][wv] = ss; }
  __syncthreads();
  if (threadIdx.x == 0) {
    s  = red[0][0] + red[0][1] + red[0][2] + red[0][3];
    ss = red[1][0] + red[1][1] + red[1][2] + red[1][3];
    float mean = s * (1.f/65536.f);
    float var  = ss * (1.f/65536.f) - mean*mean;
    stats[2*bg]   = mean;
    stats[2*bg+1] = rsqrtf(var + 1e-5f);
  }
}

// normalize + cast bf16 + transpose to token-major h_t[B][HW][C]
__global__ void gn_apply_t(const float* __restrict__ x, const float* __restrict__ stats,
                           const float* __restrict__ gw, const float* __restrict__ gb,
                           unsigned short* __restrict__ h_t) {
  __shared__ __align__(16) unsigned short tile[64][72];
  const int b = blockIdx.z, c0 = blockIdx.y * 64, hw0 = blockIdx.x * 64;
  const int t = threadIdx.x;
  {
    const int cl = t >> 2;
    const int hs = (t & 3) * 16;
    const int c  = c0 + cl;
    const int g  = c >> 4;
    const float mean = stats[2*(b*32 + g)];
    const float rstd = stats[2*(b*32 + g) + 1];
    const float w  = gw[c] * rstd;
    const float bb = gb[c] - mean * w;
    const float4* src = (const float4*)(x + ((size_t)(b*512 + c))*4096 + hw0 + hs);
    #pragma unroll
    for (int i = 0; i < 4; i++) {
      float4 vv = src[i];
      unsigned short* d = &tile[cl][hs + i*4];
      d[0] = f2bf(vv.x*w + bb); d[1] = f2bf(vv.y*w + bb);
      d[2] = f2bf(vv.z*w + bb); d[3] = f2bf(vv.w*w + bb);
    }
  }
  __syncthreads();
  {
    const int hwl = t >> 2;
    const int cs  = (t & 3) * 16;
    uint4 w0, w1;
    w0.x = pack2(tile[cs+ 0][hwl], tile[cs+ 1][hwl]);
    w0.y = pack2(tile[cs+ 2][hwl], tile[cs+ 3][hwl]);
    w0.z = pack2(tile[cs+ 4][hwl], tile[cs+ 5][hwl]);
    w0.w = pack2(tile[cs+ 6][hwl], tile[cs+ 7][hwl]);
    w1.x = pack2(tile[cs+ 8][hwl], tile[cs+ 9][hwl]);
    w1.y = pack2(tile[cs+10][hwl], tile[cs+11][hwl]);
    w1.z = pack2(tile[cs+12][hwl], tile[cs+13][hwl]);
    w1.w = pack2(tile[cs+14][hwl], tile[cs+15][hwl]);
    unsigned short* dst = h_t + ((size_t)(b*4096 + hw0 + hwl))*512 + c0 + cs;
    *(uint4*)dst       = w0;
    *(uint4*)(dst + 8) = w1;
  }
}

// fp32 -> bf16 weight cast
__global__ void castw(const float* __restrict__ src, unsigned short* __restrict__ dst, int n4) {
  int i = blockIdx.x * 256 + threadIdx.x;
  if (i < n4) {
    float4 vv = ((const float4*)src)[i];
    uint2 o;
    o.x = pack2(f2bf(vv.x), f2bf(vv.y));
    o.y = pack2(f2bf(vv.z), f2bf(vv.w));
    ((uint2*)dst)[i] = o;
  }
}

// ---------------------------------------------------------------- GEMM (bt)
// OUT[o][n] = sum_k A[o][k] * Bt[n][k]
// MODE 0: qkv epilogue -> q_t/k_t/v scatter; q pre-scaled by 0.125*log2(e)
// MODE 1: proj epilogue -> out = x + bias + acc  (fp32)
template <int MODE>
__global__ __launch_bounds__(256, 2)
void gemm_bt(const unsigned short* __restrict__ A,
             const unsigned short* __restrict__ Bt,
             unsigned short* __restrict__ q_t,
             unsigned short* __restrict__ k_t,
             unsigned short* __restrict__ v_,
             float* __restrict__ outp,
             const float* __restrict__ xres,
             const float* __restrict__ pbias) {
  __shared__ __align__(16) unsigned short As[128*32];
  __shared__ __align__(16) unsigned short Bs[128*32];
  const int b   = blockIdx.z;
  const int n0  = blockIdx.x * 128;
  const int o0  = blockIdx.y * 128;
  const int tid = threadIdx.x;
  const int wave = tid >> 6, lane = tid & 63;
  const int wr = wave >> 1, wc = wave & 1;
  const int fm = lane & 15, fq = lane >> 4;
  const int srow = lane >> 2, scol = (lane & 3) * 8;

  const unsigned short* Ab = A + (size_t)o0 * 512;
  const unsigned short* Bb = Bt + ((size_t)b*4096 + n0) * 512;

  floatx4 acc[4][4];
  #pragma unroll
  for (int i = 0; i < 4; i++)
    #pragma unroll
    for (int j = 0; j < 4; j++) acc[i][j] = (floatx4){0.f,0.f,0.f,0.f};

  for (int k0 = 0; k0 < 512; k0 += 32) {
    __syncthreads();
    #pragma unroll
    for (int cc = 0; cc < 2; cc++) {
      int ch = wave*2 + cc;
      async16(Ab + (size_t)(ch*16 + srow)*512 + k0 + scol, &As[ch*512]);
      async16(Bb + (size_t)(ch*16 + srow)*512 + k0 + scol, &Bs[ch*512]);
    }
    __syncthreads();
    short8 af[4], bf[4];
    #pragma unroll
    for (int f = 0; f < 4; f++) {
      af[f] = *(const short8*)&As[(wr*64 + f*16 + fm)*32 + fq*8];
      bf[f] = *(const short8*)&Bs[(wc*64 + f*16 + fm)*32 + fq*8];
    }
    #pragma unroll
    for (int fr = 0; fr < 4; fr++)
      #pragma unroll
      for (int fc = 0; fc < 4; fc++)
        acc[fr][fc] = __builtin_amdgcn_mfma_f32_16x16x32_bf16(af[fr], bf[fc], acc[fr][fc], 0, 0, 0);
  }

  if (MODE == 0) {
    #pragma unroll
    for (int fr = 0; fr < 4; fr++) {
      const int ob     = o0 + wr*64 + fr*16;
      const int head   = ob / 192;
      const int rem    = ob % 192;
      const int region = rem >> 6;             // 0=q 1=k 2=v
      const int dsub   = (rem & 63) + fq*4;
      const int bhh    = b*8 + head;
      #pragma unroll
      for (int fc = 0; fc < 4; fc++) {
        const int i = n0 + wc*64 + fc*16 + fm;
        if (region == 0) {
          // fold both 1/sqrt(sqrt(64)) scales AND log2(e) for max-free exp2 softmax
          unsigned short t4[4];
          #pragma unroll
          for (int r = 0; r < 4; r++) t4[r] = f2bf(acc[fr][fc][r] * 0.18033688f);
          uint2 o; o.x = pack2(t4[0], t4[1]); o.y = pack2(t4[2], t4[3]);
          *(uint2*)&q_t[((size_t)bhh*4096 + i)*64 + dsub] = o;
        } else if (region == 1) {
          unsigned short t4[4];
          #pragma unroll
          for (int r = 0; r < 4; r++) t4[r] = f2bf(acc[fr][fc][r]);
          uint2 o; o.x = pack2(t4[0], t4[1]); o.y = pack2(t4[2], t4[3]);
          *(uint2*)&k_t[((size_t)bhh*4096 + i)*64 + dsub] = o;
        } else {
          #pragma unroll
          for (int r = 0; r < 4; r++)
            v_[((size_t)bhh*64 + dsub + r)*4096 + i] = f2bf(acc[fr][fc][r]);
        }
      }
    }
  } else {
    #pragma unroll
    for (int fr = 0; fr < 4; fr++)
      #pragma unroll
      for (int fc = 0; fc < 4; fc++) {
        const int i = n0 + wc*64 + fc*16 + fm;
        #pragma unroll
        for (int r = 0; r < 4; r++) {
          const int o = o0 + wr*64 + fr*16 + fq*4 + r;
          const size_t idx = ((size_t)b*512 + o)*4096 + i;
          outp[idx] = xres[idx] + pbias[o] + acc[fr][fc][r];
        }
      }
  }
}

// ---------------------------------------------------------------- attention
// q_t,k_t: [16][4096][64] bf16 (q pre-scaled by 0.125*log2e); v: [16][64][4096]
// Max-free softmax: p = exp2(s'), per-lane l partials, no in-loop reductions.
// S computed transposed (A=K, B=Q) so each lane owns whole columns i:
//   S^T C-layout: col i = lane&15 (+16*ih), row j = jf*16 + fq*4 + r
// -> P packs 4 consecutive j per lane into one ds_write_b64 in A-layout.
__global__ __launch_bounds__(256, 2)
void attn_kernel(const unsigned short* __restrict__ q_t,
                 const unsigned short* __restrict__ k_t,
                 const unsigned short* __restrict__ v_,
                 unsigned short* __restrict__ hout_t) {
  __shared__ __align__(16) unsigned short Ks[64*72];   // [j][k], +pad
  __shared__ __align__(16) unsigned short Vs[64*72];   // [d][j], +pad
  __shared__ __align__(16) unsigned short Ps[128*72];  // [i][j], wave-private rows

  const int bh  = blockIdx.x;       // x = bh -> K/V L2 locality per XCD
  const int q0  = blockIdx.y * 128;
  const int tid = threadIdx.x;
  const int wave = tid >> 6, lane = tid & 63;
  const int fm = lane & 15, fq = lane >> 4;

  // Q B-fragments in registers for the whole loop: i = q0+wave*32+ih*16+fm
  short8 qf[2][2];
  #pragma unroll
  for (int ih = 0; ih < 2; ih++) {
    const unsigned short* qrow = q_t + ((size_t)bh*4096 + q0 + wave*32 + ih*16 + fm)*64;
    qf[ih][0] = *(const short8*)(qrow + fq*8);
    qf[ih][1] = *(const short8*)(qrow + 32 + fq*8);
  }

  floatx4 o_acc[2][4];  // [ih][df]
  #pragma unroll
  for (int a = 0; a < 2; a++)
    #pragma unroll
    for (int d = 0; d < 4; d++) o_acc[a][d] = (floatx4){0.f,0.f,0.f,0.f};
  float l0 = 0.f, l1 = 0.f;  // per-lane partial softmax denominators (cols fm, 16+fm)

  const int sr = tid >> 3;
  const int sc = (tid & 7) * 8;
  const unsigned short* kbase = k_t + (size_t)bh*262144;
  const unsigned short* vbase = v_  + (size_t)bh*262144;
  unsigned short* Pw = &Ps[(wave*32)*72];

  for (int j0 = 0; j0 < 4096; j0 += 64) {
    __syncthreads();
    {
      const unsigned short* ksrc = kbase + (size_t)j0*64;
      *(uint4*)&Ks[sr*72 + sc]      = *(const uint4*)&ksrc[(size_t)sr*64 + sc];
      *(uint4*)&Ks[(sr+32)*72 + sc] = *(const uint4*)&ksrc[(size_t)(sr+32)*64 + sc];
      const unsigned short* vsrc = vbase + j0;
      *(uint4*)&Vs[sr*72 + sc]      = *(const uint4*)&vsrc[(size_t)sr*4096 + sc];
      *(uint4*)&Vs[(sr+32)*72 + sc] = *(const uint4*)&vsrc[(size_t)(sr+32)*4096 + sc];
    }
    __syncthreads();

    // S^T = K Q^T
    floatx4 s[4][2];
    #pragma unroll
    for (int jf = 0; jf < 4; jf++) {
      short8 kf0 = *(const short8*)&Ks[(jf*16 + fm)*72 + fq*8];
      short8 kf1 = *(const short8*)&Ks[(jf*16 + fm)*72 + 32 + fq*8];
      #pragma unroll
      for (int ih = 0; ih < 2; ih++) {
        floatx4 a = (floatx4){0.f,0.f,0.f,0.f};
        a = __builtin_amdgcn_mfma_f32_16x16x32_bf16(kf0, qf[ih][0], a, 0, 0, 0);
        a = __builtin_amdgcn_mfma_f32_16x16x32_bf16(kf1, qf[ih][1], a, 0, 0, 0);
        s[jf][ih] = a;
      }
    }

    // p = exp2(s'), accumulate per-lane l, pack 4 j's -> one b64 P write
    #pragma unroll
    for (int jf = 0; jf < 4; jf++) {
      #pragma unroll
      for (int ih = 0; ih < 2; ih++) {
        float p0 = fast_exp2(s[jf][ih][0]);
        float p1 = fast_exp2(s[jf][ih][1]);
        float p2 = fast_exp2(s[jf][ih][2]);
        float p3 = fast_exp2(s[jf][ih][3]);
        if (ih) l1 += (p0 + p1) + (p2 + p3); else l0 += (p0 + p1) + (p2 + p3);
        uint2 w;
        w.x = __builtin_amdgcn_perm(rbits(p1), rbits(p0), 0x07060302u);
        w.y = __builtin_amdgcn_perm(rbits(p3), rbits(p2), 0x07060302u);
        *(uint2*)&Pw[(ih*16 + fm)*72 + jf*16 + fq*4] = w;
      }
    }

    // O += P V   (A=P rows i, B=Vs rows d)
    #pragma unroll
    for (int jc = 0; jc < 2; jc++) {
      short8 pf0 = *(const short8*)&Pw[(fm)*72      + jc*32 + fq*8];
      short8 pf1 = *(const short8*)&Pw[(16 + fm)*72 + jc*32 + fq*8];
      #pragma unroll
      for (int df = 0; df < 4; df++) {
        short8 vf = *(const short8*)&Vs[(df*16 + fm)*72 + jc*32 + fq*8];
        o_acc[0][df] = __builtin_amdgcn_mfma_f32_16x16x32_bf16(pf0, vf, o_acc[0][df], 0, 0, 0);
        o_acc[1][df] = __builtin_amdgcn_mfma_f32_16x16x32_bf16(pf1, vf, o_acc[1][df], 0, 0, 0);
      }
    }
  }

  // finalize l: reduce across fq groups (each lane then holds full sum for its column)
  l0 += __shfl_xor(l0, 16, 64); l0 += __shfl_xor(l0, 32, 64);
  l1 += __shfl_xor(l1, 16, 64); l1 += __shfl_xor(l1, 32, 64);

  const int bb = bh >> 3;
  const int cb = (bh & 7) * 64;
  #pragma unroll
  for (int ih = 0; ih < 2; ih++) {
    #pragma unroll
    for (int r = 0; r < 4; r++) {
      const int src = (lane & 48) | (fq*4 + r);       // lane holding l for row i
      const float lv = __shfl(ih ? l1 : l0, src, 64);
      const float inv = 1.f / lv;
      const int i = q0 + wave*32 + ih*16 + fq*4 + r;
      #pragma unroll
      for (int df = 0; df < 4; df++)
        hout_t[((size_t)bb*4096 + i)*512 + cb + df*16 + fm] = f2bf(o_acc[ih][df][r] * inv);
    }
  }
}

// ---------------------------------------------------------------- launcher
extern "C" void kernel_launch(void* const* d_in, const int* in_sizes, int n_in,
                              void* d_out, int out_size, void* d_ws, size_t ws_size,
                              hipStream_t stream) {
  (void)in_sizes; (void)n_in; (void)out_size; (void)ws_size;
  const float* x      = (const float*)d_in[0];
  const float* qkv_w  = (const float*)d_in[1];
  const float* proj_w = (const float*)d_in[2];
  const float* proj_b = (const float*)d_in[3];
  const float* gn_w   = (const float*)d_in[4];
  const float* gn_b   = (const float*)d_in[5];
  float* out = (float*)d_out;

  char* ws = (char*)d_ws;
  unsigned short* h_t   = (unsigned short*)(ws);                      // 8 MB, reused as hout_t
  unsigned short* q_t   = (unsigned short*)(ws + ((size_t)8  << 20));
  unsigned short* k_t   = (unsigned short*)(ws + ((size_t)16 << 20));
  unsigned short* v_    = (unsigned short*)(ws + ((size_t)24 << 20));
  unsigned short* wqkv  = (unsigned short*)(ws + ((size_t)32 << 20));
  unsigned short* wproj = (unsigned short*)(ws + ((size_t)34 << 20));
  float* stats          = (float*)(ws + ((size_t)35 << 20));
  unsigned short* hout_t = h_t;

  gn_stats<<<dim3(64), dim3(256), 0, stream>>>(x, stats);
  gn_apply_t<<<dim3(64, 8, 2), dim3(256), 0, stream>>>(x, stats, gn_w, gn_b, h_t);
  castw<<<dim3(768), dim3(256), 0, stream>>>(qkv_w, wqkv, 196608);
  castw<<<dim3(256), dim3(256), 0, stream>>>(proj_w, wproj, 65536);
  gemm_bt<0><<<dim3(32, 12, 2), dim3(256), 0, stream>>>(wqkv, h_t, q_t, k_t, v_,
                                                        nullptr, nullptr, nullptr);
  attn_kernel<<<dim3(16, 32), dim3(256), 0, stream>>>(q_t, k_t, v_, hout_t);
  gemm_bt<1><<<dim3(32, 4, 2), dim3(256), 0, stream>>>(wproj, hout_t,
                                                       nullptr, nullptr, nullptr,
                                                       out, x, proj_b);
}

// Round 3
// 227.331 us; speedup vs baseline: 1.7044x; 1.2306x over previous
//
#include <hip/hip_runtime.h>
#include <math.h>

typedef __attribute__((ext_vector_type(8))) short short8;
typedef __attribute__((ext_vector_type(4))) float floatx4;

__device__ __forceinline__ unsigned short f2bf(float f) {
  union { float f; unsigned int u; } v; v.f = f;
  unsigned int r = v.u + 0x7fffu + ((v.u >> 16) & 1u);
  return (unsigned short)(r >> 16);
}

__device__ __forceinline__ unsigned int pack2(unsigned short a, unsigned short b) {
  return (unsigned int)a | ((unsigned int)b << 16);
}

__device__ __forceinline__ unsigned int rbits(float f) {
  union { float f; unsigned int u; } v; v.f = f;
  return v.u + 0x8000u;  // round-half-up to bf16 when >>16
}

__device__ __forceinline__ float fast_exp2(float x) {
#if __has_builtin(__builtin_amdgcn_exp2f)
  return __builtin_amdgcn_exp2f(x);
#else
  return exp2f(x);
#endif
}

// async global->LDS, 16B per lane. LDS dest is wave-uniform base + lane*16.
__device__ __forceinline__ void async16(const unsigned short* gp, unsigned short* lp) {
  __builtin_amdgcn_global_load_lds(
      (__attribute__((address_space(1))) void*)(gp),
      (__attribute__((address_space(3))) void*)(lp), 16, 0, 0);
}

// ---------------------------------------------------------------- GroupNorm
__global__ void gn_stats(const float* __restrict__ x, float* __restrict__ stats) {
  int bg = blockIdx.x;
  const float4* p = (const float4*)(x + (size_t)bg * 65536);
  float s = 0.f, ss = 0.f;
  for (int i = threadIdx.x; i < 16384; i += 256) {
    float4 v = p[i];
    s  += v.x + v.y + v.z + v.w;
    ss += v.x*v.x + v.y*v.y + v.z*v.z + v.w*v.w;
  }
  #pragma unroll
  for (int off = 32; off >= 1; off >>= 1) {
    s  += __shfl_xor(s,  off, 64);
    ss += __shfl_xor(ss, off, 64);
  }
  __shared__ float red[2][4];
  int wv = threadIdx.x >> 6;
  if ((threadIdx.x & 63) == 0) { red[0][wv] = s; red[1][wv] = ss; }
  __syncthreads();
  if (threadIdx.x == 0) {
    s  = red[0][0] + red[0][1] + red[0][2] + red[0][3];
    ss = red[1][0] + red[1][1] + red[1][2] + red[1][3];
    float mean = s * (1.f/65536.f);
    float var  = ss * (1.f/65536.f) - mean*mean;
    stats[2*bg]   = mean;
    stats[2*bg+1] = rsqrtf(var + 1e-5f);
  }
}

// normalize + cast bf16 + transpose to token-major h_t[B][HW][C]
__global__ void gn_apply_t(const float* __restrict__ x, const float* __restrict__ stats,
                           const float* __restrict__ gw, const float* __restrict__ gb,
                           unsigned short* __restrict__ h_t) {
  __shared__ __align__(16) unsigned short tile[64][72];
  const int b = blockIdx.z, c0 = blockIdx.y * 64, hw0 = blockIdx.x * 64;
  const int t = threadIdx.x;
  {
    const int cl = t >> 2;
    const int hs = (t & 3) * 16;
    const int c  = c0 + cl;
    const int g  = c >> 4;
    const float mean = stats[2*(b*32 + g)];
    const float rstd = stats[2*(b*32 + g) + 1];
    const float w  = gw[c] * rstd;
    const float bb = gb[c] - mean * w;
    const float4* src = (const float4*)(x + ((size_t)(b*512 + c))*4096 + hw0 + hs);
    #pragma unroll
    for (int i = 0; i < 4; i++) {
      float4 vv = src[i];
      unsigned short* d = &tile[cl][hs + i*4];
      d[0] = f2bf(vv.x*w + bb); d[1] = f2bf(vv.y*w + bb);
      d[2] = f2bf(vv.z*w + bb); d[3] = f2bf(vv.w*w + bb);
    }
  }
  __syncthreads();
  {
    const int hwl = t >> 2;
    const int cs  = (t & 3) * 16;
    uint4 w0, w1;
    w0.x = pack2(tile[cs+ 0][hwl], tile[cs+ 1][hwl]);
    w0.y = pack2(tile[cs+ 2][hwl], tile[cs+ 3][hwl]);
    w0.z = pack2(tile[cs+ 4][hwl], tile[cs+ 5][hwl]);
    w0.w = pack2(tile[cs+ 6][hwl], tile[cs+ 7][hwl]);
    w1.x = pack2(tile[cs+ 8][hwl], tile[cs+ 9][hwl]);
    w1.y = pack2(tile[cs+10][hwl], tile[cs+11][hwl]);
    w1.z = pack2(tile[cs+12][hwl], tile[cs+13][hwl]);
    w1.w = pack2(tile[cs+14][hwl], tile[cs+15][hwl]);
    unsigned short* dst = h_t + ((size_t)(b*4096 + hw0 + hwl))*512 + c0 + cs;
    *(uint4*)dst       = w0;
    *(uint4*)(dst + 8) = w1;
  }
}

// fp32 -> bf16 weight cast
__global__ void castw(const float* __restrict__ src, unsigned short* __restrict__ dst, int n4) {
  int i = blockIdx.x * 256 + threadIdx.x;
  if (i < n4) {
    float4 vv = ((const float4*)src)[i];
    uint2 o;
    o.x = pack2(f2bf(vv.x), f2bf(vv.y));
    o.y = pack2(f2bf(vv.z), f2bf(vv.w));
    ((uint2*)dst)[i] = o;
  }
}

// ---------------------------------------------------------------- GEMM (bt)
// OUT[o][n] = sum_k A[o][k] * Bt[n][k]
// MODE 0: qkv epilogue -> q_t/k_t/v scatter; q pre-scaled by 0.125*log2(e)
// MODE 1: proj epilogue -> out = x + bias + acc  (fp32)
template <int MODE>
__global__ __launch_bounds__(256, 2)
void gemm_bt(const unsigned short* __restrict__ A,
             const unsigned short* __restrict__ Bt,
             unsigned short* __restrict__ q_t,
             unsigned short* __restrict__ k_t,
             unsigned short* __restrict__ v_,
             float* __restrict__ outp,
             const float* __restrict__ xres,
             const float* __restrict__ pbias) {
  __shared__ __align__(16) unsigned short As[128*32];
  __shared__ __align__(16) unsigned short Bs[128*32];
  const int b   = blockIdx.z;
  const int n0  = blockIdx.x * 128;
  const int o0  = blockIdx.y * 128;
  const int tid = threadIdx.x;
  const int wave = tid >> 6, lane = tid & 63;
  const int wr = wave >> 1, wc = wave & 1;
  const int fm = lane & 15, fq = lane >> 4;
  const int srow = lane >> 2, scol = (lane & 3) * 8;

  const unsigned short* Ab = A + (size_t)o0 * 512;
  const unsigned short* Bb = Bt + ((size_t)b*4096 + n0) * 512;

  floatx4 acc[4][4];
  #pragma unroll
  for (int i = 0; i < 4; i++)
    #pragma unroll
    for (int j = 0; j < 4; j++) acc[i][j] = (floatx4){0.f,0.f,0.f,0.f};

  for (int k0 = 0; k0 < 512; k0 += 32) {
    __syncthreads();
    #pragma unroll
    for (int cc = 0; cc < 2; cc++) {
      int ch = wave*2 + cc;
      async16(Ab + (size_t)(ch*16 + srow)*512 + k0 + scol, &As[ch*512]);
      async16(Bb + (size_t)(ch*16 + srow)*512 + k0 + scol, &Bs[ch*512]);
    }
    __syncthreads();
    short8 af[4], bf[4];
    #pragma unroll
    for (int f = 0; f < 4; f++) {
      af[f] = *(const short8*)&As[(wr*64 + f*16 + fm)*32 + fq*8];
      bf[f] = *(const short8*)&Bs[(wc*64 + f*16 + fm)*32 + fq*8];
    }
    #pragma unroll
    for (int fr = 0; fr < 4; fr++)
      #pragma unroll
      for (int fc = 0; fc < 4; fc++)
        acc[fr][fc] = __builtin_amdgcn_mfma_f32_16x16x32_bf16(af[fr], bf[fc], acc[fr][fc], 0, 0, 0);
  }

  if (MODE == 0) {
    #pragma unroll
    for (int fr = 0; fr < 4; fr++) {
      const int ob     = o0 + wr*64 + fr*16;
      const int head   = ob / 192;
      const int rem    = ob % 192;
      const int region = rem >> 6;             // 0=q 1=k 2=v
      const int dsub   = (rem & 63) + fq*4;
      const int bhh    = b*8 + head;
      #pragma unroll
      for (int fc = 0; fc < 4; fc++) {
        const int i = n0 + wc*64 + fc*16 + fm;
        if (region == 0) {
          // fold both 1/sqrt(sqrt(64)) scales AND log2(e) for max-free exp2 softmax
          unsigned short t4[4];
          #pragma unroll
          for (int r = 0; r < 4; r++) t4[r] = f2bf(acc[fr][fc][r] * 0.18033688f);
          uint2 o; o.x = pack2(t4[0], t4[1]); o.y = pack2(t4[2], t4[3]);
          *(uint2*)&q_t[((size_t)bhh*4096 + i)*64 + dsub] = o;
        } else if (region == 1) {
          unsigned short t4[4];
          #pragma unroll
          for (int r = 0; r < 4; r++) t4[r] = f2bf(acc[fr][fc][r]);
          uint2 o; o.x = pack2(t4[0], t4[1]); o.y = pack2(t4[2], t4[3]);
          *(uint2*)&k_t[((size_t)bhh*4096 + i)*64 + dsub] = o;
        } else {
          #pragma unroll
          for (int r = 0; r < 4; r++)
            v_[((size_t)bhh*64 + dsub + r)*4096 + i] = f2bf(acc[fr][fc][r]);
        }
      }
    }
  } else {
    #pragma unroll
    for (int fr = 0; fr < 4; fr++)
      #pragma unroll
      for (int fc = 0; fc < 4; fc++) {
        const int i = n0 + wc*64 + fc*16 + fm;
        #pragma unroll
        for (int r = 0; r < 4; r++) {
          const int o = o0 + wr*64 + fr*16 + fq*4 + r;
          const size_t idx = ((size_t)b*512 + o)*4096 + i;
          outp[idx] = xres[idx] + pbias[o] + acc[fr][fc][r];
        }
      }
  }
}

// ---------------------------------------------------------------- attention
// q_t,k_t: [16][4096][64] bf16 (q pre-scaled by 0.125*log2e); v: [16][64][4096]
// Max-free exp2 softmax, per-lane l partials. S computed transposed (A=K, B=Q).
// Software-pipelined K-loop: register prefetch + LDS double-buffer, ONE barrier
// per iter. P is wave-private (same-wave DS ops complete in order -> no barrier).
__global__ __launch_bounds__(256, 2)
void attn_kernel(const unsigned short* __restrict__ q_t,
                 const unsigned short* __restrict__ k_t,
                 const unsigned short* __restrict__ v_,
                 unsigned short* __restrict__ hout_t) {
  __shared__ __align__(16) unsigned short Ks[2][64*72];   // [j][k], +pad
  __shared__ __align__(16) unsigned short Vs[2][64*72];   // [d][j], +pad
  __shared__ __align__(16) unsigned short Ps[128*72];     // [i][j], wave-private rows

  const int bh  = blockIdx.x;       // x = bh -> K/V L2 locality per XCD
  const int q0  = blockIdx.y * 128;
  const int tid = threadIdx.x;
  const int wave = tid >> 6, lane = tid & 63;
  const int fm = lane & 15, fq = lane >> 4;

  // Q B-fragments in registers for the whole loop: i = q0+wave*32+ih*16+fm
  short8 qf[2][2];
  #pragma unroll
  for (int ih = 0; ih < 2; ih++) {
    const unsigned short* qrow = q_t + ((size_t)bh*4096 + q0 + wave*32 + ih*16 + fm)*64;
    qf[ih][0] = *(const short8*)(qrow + fq*8);
    qf[ih][1] = *(const short8*)(qrow + 32 + fq*8);
  }

  floatx4 o_acc[2][4];  // [ih][df]
  #pragma unroll
  for (int a = 0; a < 2; a++)
    #pragma unroll
    for (int d = 0; d < 4; d++) o_acc[a][d] = (floatx4){0.f,0.f,0.f,0.f};
  float l0 = 0.f, l1 = 0.f;  // per-lane partial softmax denominators

  const int sr = tid >> 3;          // 0..31 (block-wide), 8 rows per wave
  const int sc = (tid & 7) * 8;     // 16B chunks within a row
  const unsigned short* kbase = k_t + (size_t)bh*262144;
  const unsigned short* vbase = v_  + (size_t)bh*262144;
  unsigned short* Pw = &Ps[(wave*32)*72];

  // preload tile 0 into registers
  uint4 kr0 = *(const uint4*)&kbase[(size_t)sr*64 + sc];
  uint4 kr1 = *(const uint4*)&kbase[(size_t)(sr+32)*64 + sc];
  uint4 vr0 = *(const uint4*)&vbase[(size_t)sr*4096 + sc];
  uint4 vr1 = *(const uint4*)&vbase[(size_t)(sr+32)*4096 + sc];

  for (int it = 0; it < 64; it++) {
    unsigned short* Kc = Ks[it & 1];
    unsigned short* Vc = Vs[it & 1];
    // drain prefetched tile into LDS
    *(uint4*)&Kc[sr*72 + sc]      = kr0;
    *(uint4*)&Kc[(sr+32)*72 + sc] = kr1;
    *(uint4*)&Vc[sr*72 + sc]      = vr0;
    *(uint4*)&Vc[(sr+32)*72 + sc] = vr1;
    __syncthreads();

    // issue next tile's global loads (latency hidden behind compute below)
    {
      const int jn = ((it + 1) & 63) * 64;   // last iter harmlessly reloads tile 0
      kr0 = *(const uint4*)&kbase[(size_t)(jn + sr)*64 + sc];
      kr1 = *(const uint4*)&kbase[(size_t)(jn + sr + 32)*64 + sc];
      vr0 = *(const uint4*)&vbase[(size_t)sr*4096 + jn + sc];
      vr1 = *(const uint4*)&vbase[(size_t)(sr+32)*4096 + jn + sc];
    }

    // S^T = K Q^T
    floatx4 s[4][2];
    #pragma unroll
    for (int jf = 0; jf < 4; jf++) {
      short8 kf0 = *(const short8*)&Kc[(jf*16 + fm)*72 + fq*8];
      short8 kf1 = *(const short8*)&Kc[(jf*16 + fm)*72 + 32 + fq*8];
      #pragma unroll
      for (int ih = 0; ih < 2; ih++) {
        floatx4 a = (floatx4){0.f,0.f,0.f,0.f};
        a = __builtin_amdgcn_mfma_f32_16x16x32_bf16(kf0, qf[ih][0], a, 0, 0, 0);
        a = __builtin_amdgcn_mfma_f32_16x16x32_bf16(kf1, qf[ih][1], a, 0, 0, 0);
        s[jf][ih] = a;
      }
    }

    // p = exp2(s'), accumulate per-lane l, pack 4 j's -> one b64 P write
    #pragma unroll
    for (int jf = 0; jf < 4; jf++) {
      #pragma unroll
      for (int ih = 0; ih < 2; ih++) {
        float p0 = fast_exp2(s[jf][ih][0]);
        float p1 = fast_exp2(s[jf][ih][1]);
        float p2 = fast_exp2(s[jf][ih][2]);
        float p3 = fast_exp2(s[jf][ih][3]);
        if (ih) l1 += (p0 + p1) + (p2 + p3); else l0 += (p0 + p1) + (p2 + p3);
        uint2 w;
        w.x = __builtin_amdgcn_perm(rbits(p1), rbits(p0), 0x07060302u);
        w.y = __builtin_amdgcn_perm(rbits(p3), rbits(p2), 0x07060302u);
        *(uint2*)&Pw[(ih*16 + fm)*72 + jf*16 + fq*4] = w;
      }
    }
    // no barrier: Pw rows are written and read by this wave only; same-wave
    // DS ops complete in order.

    // O += P V   (A=P rows i, B=Vs rows d)
    #pragma unroll
    for (int jc = 0; jc < 2; jc++) {
      short8 pf0 = *(const short8*)&Pw[(fm)*72      + jc*32 + fq*8];
      short8 pf1 = *(const short8*)&Pw[(16 + fm)*72 + jc*32 + fq*8];
      #pragma unroll
      for (int df = 0; df < 4; df++) {
        short8 vf = *(const short8*)&Vc[(df*16 + fm)*72 + jc*32 + fq*8];
        o_acc[0][df] = __builtin_amdgcn_mfma_f32_16x16x32_bf16(pf0, vf, o_acc[0][df], 0, 0, 0);
        o_acc[1][df] = __builtin_amdgcn_mfma_f32_16x16x32_bf16(pf1, vf, o_acc[1][df], 0, 0, 0);
      }
    }
  }

  // finalize l: reduce across fq groups
  l0 += __shfl_xor(l0, 16, 64); l0 += __shfl_xor(l0, 32, 64);
  l1 += __shfl_xor(l1, 16, 64); l1 += __shfl_xor(l1, 32, 64);

  const int bb = bh >> 3;
  const int cb = (bh & 7) * 64;
  #pragma unroll
  for (int ih = 0; ih < 2; ih++) {
    #pragma unroll
    for (int r = 0; r < 4; r++) {
      const int src = (lane & 48) | (fq*4 + r);       // lane holding l for row i
      const float lv = __shfl(ih ? l1 : l0, src, 64);
      const float inv = 1.f / lv;
      const int i = q0 + wave*32 + ih*16 + fq*4 + r;
      #pragma unroll
      for (int df = 0; df < 4; df++)
        hout_t[((size_t)bb*4096 + i)*512 + cb + df*16 + fm] = f2bf(o_acc[ih][df][r] * inv);
    }
  }
}

// ---------------------------------------------------------------- launcher
extern "C" void kernel_launch(void* const* d_in, const int* in_sizes, int n_in,
                              void* d_out, int out_size, void* d_ws, size_t ws_size,
                              hipStream_t stream) {
  (void)in_sizes; (void)n_in; (void)out_size; (void)ws_size;
  const float* x      = (const float*)d_in[0];
  const float* qkv_w  = (const float*)d_in[1];
  const float* proj_w = (const float*)d_in[2];
  const float* proj_b = (const float*)d_in[3];
  const float* gn_w   = (const float*)d_in[4];
  const float* gn_b   = (const float*)d_in[5];
  float* out = (float*)d_out;

  char* ws = (char*)d_ws;
  unsigned short* h_t   = (unsigned short*)(ws);                      // 8 MB, reused as hout_t
  unsigned short* q_t   = (unsigned short*)(ws + ((size_t)8  << 20));
  unsigned short* k_t   = (unsigned short*)(ws + ((size_t)16 << 20));
  unsigned short* v_    = (unsigned short*)(ws + ((size_t)24 << 20));
  unsigned short* wqkv  = (unsigned short*)(ws + ((size_t)32 << 20));
  unsigned short* wproj = (unsigned short*)(ws + ((size_t)34 << 20));
  float* stats          = (float*)(ws + ((size_t)35 << 20));
  unsigned short* hout_t = h_t;

  gn_stats<<<dim3(64), dim3(256), 0, stream>>>(x, stats);
  gn_apply_t<<<dim3(64, 8, 2), dim3(256), 0, stream>>>(x, stats, gn_w, gn_b, h_t);
  castw<<<dim3(768), dim3(256), 0, stream>>>(qkv_w, wqkv, 196608);
  castw<<<dim3(256), dim3(256), 0, stream>>>(proj_w, wproj, 65536);
  gemm_bt<0><<<dim3(32, 12, 2), dim3(256), 0, stream>>>(wqkv, h_t, q_t, k_t, v_,
                                                        nullptr, nullptr, nullptr);
  attn_kernel<<<dim3(16, 32), dim3(256), 0, stream>>>(q_t, k_t, v_, hout_t);
  gemm_bt<1><<<dim3(32, 4, 2), dim3(256), 0, stream>>>(wproj, hout_t,
                                                       nullptr, nullptr, nullptr,
                                                       out, x, proj_b);
}